// Round 9
// baseline (3618.335 us; speedup 1.0000x reference)
//
#include <hip/hip_runtime.h>

#define TSTEPS 2048
#define PPB 16          // paths per block
#define NT 256          // 4 waves; wave wv = column tile; each wave does BOTH MLPs
#define KAPPA 2.72f
#define THETA -3.5f

typedef _Float16 half8 __attribute__((ext_vector_type(8)));
typedef float f32x4 __attribute__((ext_vector_type(4)));

__device__ __forceinline__ float ftanh(float x) {
    float e = __expf(2.0f * x);                        // native v_exp path
    return 1.0f - 2.0f * __builtin_amdgcn_rcpf(e + 1.0f);
}
__device__ __forceinline__ f32x4 mm(half8 a, half8 b, f32x4 c) {
    return __builtin_amdgcn_mfma_f32_16x16x32_f16(a, b, c, 0, 0, 0);
}
__device__ __forceinline__ void wsplit(float v, _Float16& h, _Float16& l) {
    h = (_Float16)v; l = (_Float16)(v - (float)h);
}

// tanh via LDS LUT: 512 intervals over [-5,5], entry = (tanh(x_i), tanh(x_{i+1})-tanh(x_i)).
// Max interp error ~3.7e-5; |x|>5 clamps to tanh(5)=0.99991 (9e-5 err).
__device__ __forceinline__ float lut_tanh(const float2* lut, float x) {
    float u = fmaf(x, 51.2f, 256.0f);          // (x+5)/h, h = 10/512
    u = fminf(fmaxf(u, 0.0f), 511.9995f);      // med3 clamp
    float fl = floorf(u);
    const float2 e = lut[(int)fl];
    return fmaf(u - fl, e.y, e.x);
}

// LDS f16 activation rows: [row 0..15][slot 0..7][elem 0..7], slot = chunk ^ (row&7).

__global__ __launch_bounds__(NT, 2) void sim_kernel(
    const float* __restrict__ init_var, const float* __restrict__ dtp,
    const float* __restrict__ dwg,
    const float* __restrict__ dW0, const float* __restrict__ dB0,
    const float* __restrict__ dW1, const float* __restrict__ dB1,
    const float* __restrict__ dW2, const float* __restrict__ dB2,
    const float* __restrict__ dW3, const float* __restrict__ dB3,
    const float* __restrict__ fW0, const float* __restrict__ fB0,
    const float* __restrict__ fW1, const float* __restrict__ fB1,
    const float* __restrict__ fW2, const float* __restrict__ fB2,
    const float* __restrict__ fW3, const float* __restrict__ fB3,
    float* __restrict__ out)
{
    __shared__ __align__(16) _Float16 hA[2][1024];
    __shared__ __align__(16) _Float16 hB[2][1024];
    __shared__ __align__(16) _Float16 hC[2][1024];
    __shared__ __align__(16) float2 tanhLUT[512];

    const int tid  = threadIdx.x;
    const int lane = tid & 63;
    const int wv   = tid >> 6;        // 0..3 column tile
    const int l15  = lane & 15;
    const int lg   = lane >> 4;       // 0..3
    const int col  = wv * 16 + l15;   // column this lane supplies (B) / owns (C)
    const int q    = l15 & 7;

    // ---- build tanh LUT (one-time) ----
    for (int i = tid; i < 512; i += NT) {
        const float hstep = 10.0f / 512.0f;
        const float x0 = -5.0f + i * hstep;
        const float v0 = ftanh(x0), v1 = ftanh(x0 + hstep);
        tanhLUT[i] = make_float2(v0, v1 - v0);
    }

    const int roff0 = l15 * 64 + ((lg ^ q) << 3);         // chunks 0-3 (K 0..31)
    const int roff1 = l15 * 64 + (((4 + lg) ^ q) << 3);   // chunks 4-7 (K 32..63)
    int woff[4];
#pragma unroll
    for (int r = 0; r < 4; ++r) {
        const int wrow = lg * 4 + r;
        woff[r] = wrow * 64 + ((((col >> 3) ^ (wrow & 7))) << 3) + (col & 7);
    }

    // ---------------- B-fragments: 16 half8 = 64 VGPR ----------------
    half8 bd0h, bd0l, bf0h, bf0l;
#pragma unroll
    for (int i = 0; i < 8; ++i) {
        const int idx = (lg & 1) * 8 + i;
        const float vd = (idx < 15) ? dW0[col * 15 + idx] : 0.f;
        const float vf = (idx < 15) ? fW0[col * 15 + idx] : 0.f;
        _Float16 h, l;
        wsplit(vd, h, l); bd0h[i] = h; bd0l[i] = l;
        wsplit(vf, h, l); bf0h[i] = h; bf0l[i] = l;
    }
    half8 bd1h0, bd1h1, bd2h0, bd2h1;
    half8 bf1h0, bf1h1, bf2h0, bf2h1;
#pragma unroll
    for (int i = 0; i < 8; ++i) {
        const int ka = lg * 8 + i, kb = 32 + lg * 8 + i;
        bd1h0[i] = (_Float16)dW1[col * 64 + ka];
        bd1h1[i] = (_Float16)dW1[col * 64 + kb];
        bd2h0[i] = (_Float16)dW2[col * 64 + ka];
        bd2h1[i] = (_Float16)dW2[col * 64 + kb];
        bf1h0[i] = (_Float16)fW1[col * 64 + ka];
        bf1h1[i] = (_Float16)fW1[col * 64 + kb];
        bf2h0[i] = (_Float16)fW2[col * 64 + ka];
        bf2h1[i] = (_Float16)fW2[col * 64 + kb];
    }
    half8 w3d0, w3d1, w3f0, w3f1;
#pragma unroll
    for (int i = 0; i < 8; ++i) {
        const int ka = lg * 8 + i, kb = 32 + lg * 8 + i;
        w3d0[i] = (_Float16)dW3[ka];
        w3d1[i] = (_Float16)dW3[kb];
        w3f0[i] = (_Float16)fW3[ka];
        w3f1[i] = (_Float16)fW3[kb];
    }
    // Pin weight fragments so their load+split chains can't be rematerialized in-loop.
    asm volatile("" : "+v"(bd0h), "+v"(bd0l), "+v"(bf0h), "+v"(bf0l));
    asm volatile("" : "+v"(bd1h0), "+v"(bd1h1), "+v"(bd2h0), "+v"(bd2h1));
    asm volatile("" : "+v"(bf1h0), "+v"(bf1h1), "+v"(bf2h0), "+v"(bf2h1));
    asm volatile("" : "+v"(w3d0), "+v"(w3d1), "+v"(w3f0), "+v"(w3f1));

    const float biasd0 = dB0[col], biasd1 = dB1[col], biasd2 = dB2[col];
    const float biasf0 = fB0[col], biasf1 = fB1[col], biasf2 = fB2[col];
    const float b3d = dB3[0], b3f = fB3[0];
    const float dt  = dtp[0];

    // ---------------- replicated per-lane state (p = l15) ----------------
    const int p = l15;
    const int path = blockIdx.x * PPB + p;
    const size_t pathT = (size_t)path * TSTEPS;
    const float* dwp = dwg + pathT;
    float iv = fminf(fmaxf(init_var[path], 0.01f), 1.5f);
    float lv = __logf(iv);
    float s1a0 = 0.f, s1a1 = 0.f;
    float s2a0 = 0.f, s2a1 = 0.f, s2a2 = 0.f, s2a3 = 0.f;
    float s3a0 = 0.f, s3a1 = 0.f, s3a2 = 0.f, s3a3 = 0.f;
    float s3a4 = 0.f, s3a5 = 0.f, s3a6 = 0.f, s3a7 = 0.f;

    const bool selHi = (lg & 1) != 0;   // lane's L0 A-frag covers x[8..15]
    const bool selLo = (lg & 2) != 0;   // lane's L0 A-frag carries the lo split

    __syncthreads();                    // LUT ready

    for (int t = 0; t < TSTEPS; ++t) {
        const float dwv = dwp[t];

        // ---- build L0 A-fragment in-register from own state ----
        half8 a0;
        {
            float xv[8];
            xv[0] = selHi ? s3a2 : s1a0;
            xv[1] = selHi ? s3a3 : s1a1;
            xv[2] = selHi ? s3a4 : s2a0;
            xv[3] = selHi ? s3a5 : s2a1;
            xv[4] = selHi ? s3a6 : s2a2;
            xv[5] = selHi ? s3a7 : s2a3;
            xv[6] = selHi ? (lv + 4.0f) : s3a0;
            xv[7] = selHi ? 0.f : s3a1;
#pragma unroll
            for (int i = 0; i < 8; ++i) {
                _Float16 h, l; wsplit(xv[i], h, l);
                a0[i] = selLo ? l : h;
            }
        }

        // ---- L0: x -> h0 (both MLPs, 2 MFMA each, exact hi/lo) ----
        {
            f32x4 cd = {biasd0, biasd0, biasd0, biasd0};
            f32x4 cf = {biasf0, biasf0, biasf0, biasf0};
            cd = mm(a0, bd0h, cd);  cf = mm(a0, bf0h, cf);
            cd = mm(a0, bd0l, cd);  cf = mm(a0, bf0l, cf);
#pragma unroll
            for (int r = 0; r < 4; ++r) {
                hA[0][woff[r]] = (_Float16)lut_tanh(tanhLUT, cd[r]);
                hA[1][woff[r]] = (_Float16)lut_tanh(tanhLUT, cf[r]);
            }
        }
        __syncthreads();

        // ---- L1: h0 -> h1 (f16 weights) ----
        {
            const half8 ad0 = *(const half8*)(&hA[0][roff0]);
            const half8 ad1 = *(const half8*)(&hA[0][roff1]);
            const half8 af0 = *(const half8*)(&hA[1][roff0]);
            const half8 af1 = *(const half8*)(&hA[1][roff1]);
            f32x4 cd = {biasd1, biasd1, biasd1, biasd1};
            f32x4 cf = {biasf1, biasf1, biasf1, biasf1};
            cd = mm(ad0, bd1h0, cd);  cf = mm(af0, bf1h0, cf);
            cd = mm(ad1, bd1h1, cd);  cf = mm(af1, bf1h1, cf);
#pragma unroll
            for (int r = 0; r < 4; ++r) {
                hB[0][woff[r]] = (_Float16)lut_tanh(tanhLUT, cd[r]);
                hB[1][woff[r]] = (_Float16)lut_tanh(tanhLUT, cf[r]);
            }
        }
        __syncthreads();

        // ---- L2: h1 -> h2 ----
        {
            const half8 ad0 = *(const half8*)(&hB[0][roff0]);
            const half8 ad1 = *(const half8*)(&hB[0][roff1]);
            const half8 af0 = *(const half8*)(&hB[1][roff0]);
            const half8 af1 = *(const half8*)(&hB[1][roff1]);
            f32x4 cd = {biasd2, biasd2, biasd2, biasd2};
            f32x4 cf = {biasf2, biasf2, biasf2, biasf2};
            cd = mm(ad0, bd2h0, cd);  cf = mm(af0, bf2h0, cf);
            cd = mm(ad1, bd2h1, cd);  cf = mm(af1, bf2h1, cf);
#pragma unroll
            for (int r = 0; r < 4; ++r) {
                hC[0][woff[r]] = (_Float16)lut_tanh(tanhLUT, cd[r]);
                hC[1][woff[r]] = (_Float16)lut_tanh(tanhLUT, cf[r]);
            }
        }
        __syncthreads();

        // ---- L3: od/of broadcast to all lanes via w3-replicated A ----
        float od, of;
        {
            const half8 bd0 = *(const half8*)(&hC[0][roff0]);
            const half8 bd1 = *(const half8*)(&hC[0][roff1]);
            const half8 bf0 = *(const half8*)(&hC[1][roff0]);
            const half8 bf1 = *(const half8*)(&hC[1][roff1]);
            f32x4 c3d = {0.f, 0.f, 0.f, 0.f}, c3f = {0.f, 0.f, 0.f, 0.f};
            c3d = mm(w3d0, bd0, c3d);  c3f = mm(w3f0, bf0, c3f);
            c3d = mm(w3d1, bd1, c3d);  c3f = mm(w3f1, bf1, c3f);
            od = c3d[0] + b3d;          // same value in all C rows
            of = c3f[0] + b3f;
        }

        // ---- replicated state update (all lanes, p = l15) ----
        {
            const float drift_nn = 0.5f * lut_tanh(tanhLUT, od);
            // 1.5*sigmoid(of)+0.1 == 0.85 + 0.75*tanh(of/2)
            const float diffu = fmaf(0.75f, lut_tanh(tanhLUT, 0.5f * of), 0.85f);
            float lvn = lv + KAPPA * (THETA - lv) * dt + drift_nn * dt + diffu * dwv;
            lvn = fminf(fmaxf(lvn, -5.0f), 1.0f);
            const float d = lvn - lv;
            const float o0 = dt * dt, o1 = dt * d, o2 = d * dt, o3 = d * d;
            const float c6 = 1.0f / 6.0f;
            s3a0 += s2a0 * dt + s1a0 * 0.5f * o0 + dt * o0 * c6;
            s3a1 += s2a0 * d  + s1a0 * 0.5f * o1 + dt * o1 * c6;
            s3a2 += s2a1 * dt + s1a0 * 0.5f * o2 + dt * o2 * c6;
            s3a3 += s2a1 * d  + s1a0 * 0.5f * o3 + dt * o3 * c6;
            s3a4 += s2a2 * dt + s1a1 * 0.5f * o0 + d * o0 * c6;
            s3a5 += s2a2 * d  + s1a1 * 0.5f * o1 + d * o1 * c6;
            s3a6 += s2a3 * dt + s1a1 * 0.5f * o2 + d * o2 * c6;
            s3a7 += s2a3 * d  + s1a1 * 0.5f * o3 + d * o3 * c6;
            s2a0 += s1a0 * dt + 0.5f * o0;  s2a1 += s1a0 * d + 0.5f * o1;
            s2a2 += s1a1 * dt + 0.5f * o2;  s2a3 += s1a1 * d + 0.5f * o3;
            s1a0 += dt;  s1a1 += d;
            if (tid < 16) out[pathT + t] = __expf(lvn);   // wave 0, lanes 0-15
            lv = lvn;
        }
        // Race-freedom: hA(t+1) written after B3(t), last hA read pre-B2(t);
        // hB(t+1) after B1(t+1), last read pre-B3(t); hC(t+1) after B2(t+1),
        // last read (L3) pre-B1(t+1) in every wave's program order.
    }
}

extern "C" void kernel_launch(void* const* d_in, const int* in_sizes, int n_in,
                              void* d_out, int out_size, void* d_ws, size_t ws_size,
                              hipStream_t stream) {
    const float* init_var = (const float*)d_in[0];
    const float* dtp      = (const float*)d_in[1];
    const float* dwg      = (const float*)d_in[2];
    const float* dW0 = (const float*)d_in[3];
    const float* dB0 = (const float*)d_in[4];
    const float* dW1 = (const float*)d_in[5];
    const float* dB1 = (const float*)d_in[6];
    const float* dW2 = (const float*)d_in[7];
    const float* dB2 = (const float*)d_in[8];
    const float* dW3 = (const float*)d_in[9];
    const float* dB3 = (const float*)d_in[10];
    const float* fW0 = (const float*)d_in[11];
    const float* fB0 = (const float*)d_in[12];
    const float* fW1 = (const float*)d_in[13];
    const float* fB1 = (const float*)d_in[14];
    const float* fW2 = (const float*)d_in[15];
    const float* fB2 = (const float*)d_in[16];
    const float* fW3 = (const float*)d_in[17];
    const float* fB3 = (const float*)d_in[18];
    float* out = (float*)d_out;

    sim_kernel<<<dim3(8192 / PPB), dim3(NT), 0, stream>>>(
        init_var, dtp, dwg,
        dW0, dB0, dW1, dB1, dW2, dB2, dW3, dB3,
        fW0, fB0, fW1, fB1, fW2, fB2, fW3, fB3,
        out);
}